// Round 2
// baseline (138.260 us; speedup 1.0000x reference)
//
#include <hip/hip_runtime.h>
#include <hip/hip_bf16.h>

// Attention fwd: out = softmax(QK^T/scale + mask) V
// B=2 H=16 SQ=SKV=2048 D=64, fp32 in/out, bf16 MFMA compute.

#define NB 2
#define NH 16
#define NSQ 2048
#define NSKV 2048
#define ND 64

typedef __attribute__((ext_vector_type(8))) short bf16x8;
typedef __attribute__((ext_vector_type(4))) float f32x4;

__device__ __forceinline__ short f2bf(float x) {
  // round-to-nearest-even f32 -> bf16 (inputs are finite normals)
  union { float f; unsigned u; } c; c.f = x;
  unsigned r = c.u + 0x7fffu + ((c.u >> 16) & 1u);
  return (short)(r >> 16);
}

__global__ __launch_bounds__(256, 4)
void attn_fwd(const float* __restrict__ Q, const float* __restrict__ K,
              const float* __restrict__ V, const float* __restrict__ M,
              const void* __restrict__ scale_p, float* __restrict__ O)
{
  const int qb  = blockIdx.x;   // q block of 64 rows
  const int bh  = blockIdx.y;   // fused b*H+h
  const int tid = (int)threadIdx.x;
  const int wv  = tid >> 6;
  const int ln  = tid & 63;
  const int l16 = ln & 15;
  const int lq  = ln >> 4;

  // scale arrives as a 1-element array; Python `8` is int32, but accept
  // float too: pick whichever interpretation is a sane magnitude.
  float scale_v;
  {
    union { int i; float f; } u;
    u.i = ((const int*)scale_p)[0];
    float af = fabsf(u.f);
    scale_v = (af >= 1e-6f && af <= 1e6f) ? u.f : (float)u.i;
  }
  const float inv_scale = 1.0f / scale_v;

  const float* Qb = Q + (size_t)bh * NSQ * ND;
  const float* Kb = K + (size_t)bh * NSKV * ND;
  const float* Vb = V + (size_t)bh * NSKV * ND;

  const int q0 = qb * 64;

  // +8 bf16 pad -> 144B row stride: 16B-aligned for b128, 2-way-free banks
  __shared__ short Kl[64][72];
  __shared__ short Vt[64][72];      // Vt[d][kv]
  __shared__ short Pl[4][16][72];   // per-wave P buffer

  // Q fragments, held in registers for the whole KV loop.
  // A-frag: lane holds Q[l%16][kc*32 + 8*(l/16) + j], j=0..7
  bf16x8 qf[2];
  {
    const float* qrow = Qb + (size_t)(q0 + wv * 16 + l16) * ND;
#pragma unroll
    for (int kc = 0; kc < 2; ++kc) {
      const float4* p = (const float4*)(qrow + kc * 32 + lq * 8);
      float4 a = p[0], b = p[1];
      bf16x8 f;
      f[0]=f2bf(a.x); f[1]=f2bf(a.y); f[2]=f2bf(a.z); f[3]=f2bf(a.w);
      f[4]=f2bf(b.x); f[5]=f2bf(b.y); f[6]=f2bf(b.z); f[7]=f2bf(b.w);
      qf[kc] = f;
    }
  }

  // online softmax state; reg r of acc = q-row (lq*4+r) within the wave's 16
  float m_r[4], l_r[4];
  f32x4 oa[4];   // oa[nt]: D cols nt*16+l16
#pragma unroll
  for (int r = 0; r < 4; ++r) { m_r[r] = -1e30f; l_r[r] = 0.0f; }
#pragma unroll
  for (int nt = 0; nt < 4; ++nt) { f32x4 z = {0.f,0.f,0.f,0.f}; oa[nt] = z; }

  const float* mbase = M + (size_t)(q0 + wv * 16) * NSKV;

  for (int kvb = 0; kvb < NSKV; kvb += 64) {
    // ---- stage K tile [64 kv][64 d] as bf16 (coalesced float4 reads)
    {
      const int row = tid >> 2;
      const int dch = (tid & 3) << 4;
      const float4* src = (const float4*)(Kb + (size_t)(kvb + row) * ND + dch);
      float4 a0 = src[0], a1 = src[1], a2 = src[2], a3 = src[3];
      bf16x8 w0, w1;
      w0[0]=f2bf(a0.x); w0[1]=f2bf(a0.y); w0[2]=f2bf(a0.z); w0[3]=f2bf(a0.w);
      w0[4]=f2bf(a1.x); w0[5]=f2bf(a1.y); w0[6]=f2bf(a1.z); w0[7]=f2bf(a1.w);
      w1[0]=f2bf(a2.x); w1[1]=f2bf(a2.y); w1[2]=f2bf(a2.z); w1[3]=f2bf(a2.w);
      w1[4]=f2bf(a3.x); w1[5]=f2bf(a3.y); w1[6]=f2bf(a3.z); w1[7]=f2bf(a3.w);
      *(bf16x8*)&Kl[row][dch]     = w0;
      *(bf16x8*)&Kl[row][dch + 8] = w1;
    }
    // ---- stage V transposed: Vt[d][kv]; lane=d -> global reads 256B-contig
    {
      const int d  = tid & 63;
      const int kh = (tid >> 6) << 4;
      const float* src = Vb + (size_t)(kvb + kh) * ND + d;
      bf16x8 w0, w1;
#pragma unroll
      for (int j = 0; j < 8; ++j) w0[j] = f2bf(src[(size_t)j * ND]);
#pragma unroll
      for (int j = 0; j < 8; ++j) w1[j] = f2bf(src[(size_t)(j + 8) * ND]);
      *(bf16x8*)&Vt[d][kh]     = w0;
      *(bf16x8*)&Vt[d][kh + 8] = w1;
    }
    __syncthreads();

    // ---- S = Q K^T  (per wave: 16 q-rows x 64 kv)
    f32x4 s[4];
#pragma unroll
    for (int nt = 0; nt < 4; ++nt) {
      f32x4 acc = {0.f,0.f,0.f,0.f};
#pragma unroll
      for (int kc = 0; kc < 2; ++kc) {
        bf16x8 kf = *(const bf16x8*)&Kl[nt * 16 + l16][kc * 32 + lq * 8];
        acc = __builtin_amdgcn_mfma_f32_16x16x32_bf16(qf[kc], kf, acc, 0, 0, 0);
      }
      s[nt] = acc;
    }

    // ---- scale + additive mask (mask broadcast over b,h)
#pragma unroll
    for (int r = 0; r < 4; ++r) {
      const float* mrow = mbase + (size_t)(lq * 4 + r) * NSKV + kvb;
#pragma unroll
      for (int nt = 0; nt < 4; ++nt)
        s[nt][r] = s[nt][r] * inv_scale + mrow[nt * 16 + l16];
    }

    // ---- online softmax: row max across 4 nt (in-lane) + 16 lanes (shfl)
#pragma unroll
    for (int r = 0; r < 4; ++r) {
      float mx = fmaxf(fmaxf(s[0][r], s[1][r]), fmaxf(s[2][r], s[3][r]));
      mx = fmaxf(mx, __shfl_xor(mx, 1, 64));
      mx = fmaxf(mx, __shfl_xor(mx, 2, 64));
      mx = fmaxf(mx, __shfl_xor(mx, 4, 64));
      mx = fmaxf(mx, __shfl_xor(mx, 8, 64));
      float mnew = fmaxf(m_r[r], mx);
      float al = __expf(m_r[r] - mnew);
      m_r[r] = mnew;
      l_r[r] *= al;
#pragma unroll
      for (int nt = 0; nt < 4; ++nt) oa[nt][r] *= al;
    }

    // ---- P = exp(s - m), row-sum, write bf16 P to wave-private LDS
#pragma unroll
    for (int r = 0; r < 4; ++r) {
      float ps = 0.f;
#pragma unroll
      for (int nt = 0; nt < 4; ++nt) {
        float p = __expf(s[nt][r] - m_r[r]);
        ps += p;
        Pl[wv][lq * 4 + r][nt * 16 + l16] = f2bf(p);
      }
      ps += __shfl_xor(ps, 1, 64);
      ps += __shfl_xor(ps, 2, 64);
      ps += __shfl_xor(ps, 4, 64);
      ps += __shfl_xor(ps, 8, 64);
      l_r[r] += ps;
    }

    // ---- O += P V  (P A-frags via LDS transpose; Vt rows give B-frags)
#pragma unroll
    for (int kc = 0; kc < 2; ++kc) {
      bf16x8 pf = *(const bf16x8*)&Pl[wv][l16][kc * 32 + lq * 8];
#pragma unroll
      for (int nt = 0; nt < 4; ++nt) {
        bf16x8 vf = *(const bf16x8*)&Vt[nt * 16 + l16][kc * 32 + lq * 8];
        oa[nt] = __builtin_amdgcn_mfma_f32_16x16x32_bf16(pf, vf, oa[nt], 0, 0, 0);
      }
    }
    __syncthreads();   // protect Kl/Vt before next stage
  }

  // ---- epilogue: normalize and store fp32
#pragma unroll
  for (int r = 0; r < 4; ++r) {
    const float invl = 1.0f / l_r[r];
    float* orow = O + ((size_t)bh * NSQ + q0 + wv * 16 + lq * 4 + r) * ND;
#pragma unroll
    for (int nt = 0; nt < 4; ++nt)
      orow[nt * 16 + l16] = oa[nt][r] * invl;
  }
}

extern "C" void kernel_launch(void* const* d_in, const int* in_sizes, int n_in,
                              void* d_out, int out_size, void* d_ws, size_t ws_size,
                              hipStream_t stream) {
  const float* q     = (const float*)d_in[0];
  const float* k     = (const float*)d_in[1];
  const float* v     = (const float*)d_in[2];
  const float* mask  = (const float*)d_in[3];
  const void*  scale = (const void*)d_in[4];
  float* out = (float*)d_out;

  dim3 grid(NSQ / 64, NB * NH);   // x = qblock (consecutive blocks share K/V in L2)
  attn_fwd<<<grid, 256, 0, stream>>>(q, k, v, mask, scale, out);
}